// Round 4
// baseline (401.290 us; speedup 1.0000x reference)
//
#include <hip/hip_runtime.h>
#include <math.h>

#define B_SZ 4
#define N_SEQ 2048
#define D_DIM 256
#define H_HEADS 4
#define E_DIM 256
#define ROWS (B_SZ*N_SEQ)
#define PAD_TOK -2.0f
#define LN_EPS 1e-6f

typedef __attribute__((ext_vector_type(8))) short short8;   // 8 x bf16 (4 VGPRs)
typedef __attribute__((ext_vector_type(4))) float f32x4;

static __device__ __forceinline__ unsigned short f2bf(float f){
  union { float f; unsigned u; } v; v.f = f;
  unsigned r = v.u + 0x7fffu + ((v.u >> 16) & 1u);
  return (unsigned short)(r >> 16);
}
static __device__ __forceinline__ float bf2f(unsigned short s){
  union { unsigned u; float f; } v; v.u = ((unsigned)s) << 16; return v.f;
}
static __device__ __forceinline__ f32x4 mfma16(short8 a, short8 b, f32x4 c){
  return __builtin_amdgcn_mfma_f32_16x16x32_bf16(a, b, c, 0, 0, 0);
}

// async global->LDS, 16B per lane; LDS dest must be wave-linear (base + lane*16)
#define GLOAD_LDS16(gsrc, ldst) \
  __builtin_amdgcn_global_load_lds((const __attribute__((address_space(1))) void*)(gsrc), \
                                   (__attribute__((address_space(3))) void*)(ldst), 16, 0, 0)

// ---------------- Kernel 1: input LN -> bf16 x_norm, mask value ----------------
__global__ __launch_bounds__(256) void k_ln_in(
    const float* __restrict__ x, const float* __restrict__ mask,
    const float* __restrict__ g, const float* __restrict__ bta,
    unsigned short* __restrict__ xn, float* __restrict__ mval){
  int row = blockIdx.x * 4 + (threadIdx.x >> 6);
  int lane = threadIdx.x & 63;
  const float* xr = x + (size_t)row * D_DIM + lane * 4;
  f32x4 v = *reinterpret_cast<const f32x4*>(xr);
  float s = v[0]+v[1]+v[2]+v[3];
  float q = v[0]*v[0]+v[1]*v[1]+v[2]*v[2]+v[3]*v[3];
  #pragma unroll
  for (int m=1;m<64;m<<=1){ s += __shfl_xor(s,m,64); q += __shfl_xor(q,m,64); }
  float mean = s * (1.0f/D_DIM);
  float var  = q * (1.0f/D_DIM) - mean*mean;
  float rs = rsqrtf(var + LN_EPS);
  int c = lane*4;
  ushort4 o;
  o.x = f2bf((v[0]-mean)*rs*g[c+0] + bta[c+0]);
  o.y = f2bf((v[1]-mean)*rs*g[c+1] + bta[c+1]);
  o.z = f2bf((v[2]-mean)*rs*g[c+2] + bta[c+2]);
  o.w = f2bf((v[3]-mean)*rs*g[c+3] + bta[c+3]);
  *reinterpret_cast<ushort4*>(xn + (size_t)row*D_DIM + c) = o;
  if (lane == 0) mval[row] = (mask[row] == PAD_TOK) ? 0.0f : 1.0f;
}

// ---------------- Kernel 2a: transpose QKVG weights -> wt[mat][e][d] bf16 ----------------
__global__ __launch_bounds__(256) void k_prep_w(
    const float* __restrict__ Wq, const float* __restrict__ Wk,
    const float* __restrict__ Wv, const float* __restrict__ Wg,
    unsigned short* __restrict__ wt){
  int mat = blockIdx.z; int proj = mat >> 2, h = mat & 3;
  const float* W = (proj==0 ? Wq : (proj==1 ? Wk : (proj==2 ? Wv : Wg))) + (size_t)h * D_DIM * E_DIM;
  __shared__ float tile[64][65];
  int e0 = blockIdx.x*64, d0 = blockIdx.y*64;
  #pragma unroll
  for (int i=0;i<16;i++){
    int idx = threadIdx.x + i*256;
    int dl = idx >> 6, el = idx & 63;
    tile[dl][el] = W[(size_t)(d0+dl)*E_DIM + e0 + el];
  }
  __syncthreads();
  #pragma unroll
  for (int i=0;i<16;i++){
    int idx = threadIdx.x + i*256;
    int el = idx >> 6, dl = idx & 63;
    wt[((size_t)mat*E_DIM + e0+el)*D_DIM + d0+dl] = f2bf(tile[dl][el]);
  }
}

// ------- Kernel 2b: out_w [e*H+h][col] -> owt[col][h*256+e] bf16 (B^T, perm baked) -------
__global__ __launch_bounds__(256) void k_prep_ow(
    const float* __restrict__ out_w, unsigned short* __restrict__ owt){
  int c0 = blockIdx.x*64;            // c' = h*256+e tile base
  int col0 = blockIdx.y*64;
  int hh = c0 >> 8; int e0 = c0 & 255;
  __shared__ float tile[64][65];
  #pragma unroll
  for (int i=0;i<16;i++){
    int idx = threadIdx.x + i*256;
    int el = idx>>6, cl = idx&63;
    tile[el][cl] = out_w[(size_t)((e0+el)*H_HEADS + hh)*E_DIM + col0+cl];
  }
  __syncthreads();
  #pragma unroll
  for (int i=0;i<16;i++){
    int idx = threadIdx.x + i*256;
    int cl = idx>>6, el = idx&63;
    owt[(size_t)(col0+cl)*1024 + c0 + el] = f2bf(tile[el][cl]);
  }
}

// ------- Kernel 3: batched projections q,k,gate (+v transposed); 32 rows/wave -------
__global__ __launch_bounds__(256,2) void k_proj(
    const unsigned short* __restrict__ xn, const unsigned short* __restrict__ wt,
    unsigned short* __restrict__ qb, unsigned short* __restrict__ kb,
    unsigned short* __restrict__ vtb, unsigned short* __restrict__ gpb){
  int mat = blockIdx.y; int proj = mat >> 2, h = mat & 3;
  int wv = threadIdx.x >> 6, lane = threadIdx.x & 63;
  int lr = lane & 15, lg = lane >> 4;
  int r0 = blockIdx.x * 128 + wv * 32;
  const unsigned short* wm = wt + (size_t)mat * D_DIM * E_DIM;
  short8 a[2][8];
  #pragma unroll
  for (int qr=0;qr<2;qr++){
    const unsigned short* arow = xn + (size_t)(r0 + qr*16 + lr) * D_DIM + lg*8;
    #pragma unroll
    for (int kk=0;kk<8;kk++) a[qr][kk] = *reinterpret_cast<const short8*>(arow + kk*32);
  }
  unsigned short* outp = (proj==0 ? qb : (proj==1 ? kb : gpb)) + (size_t)h * ROWS * E_DIM;
  #pragma unroll 2
  for (int nt=0; nt<16; nt++){
    f32x4 acc0 = f32x4{0.f,0.f,0.f,0.f};
    f32x4 acc1 = f32x4{0.f,0.f,0.f,0.f};
    const unsigned short* brow = wm + (size_t)(nt*16 + lr) * D_DIM + lg*8;
    #pragma unroll
    for (int kk=0;kk<8;kk++){
      short8 bfrag = *reinterpret_cast<const short8*>(brow + kk*32);
      acc0 = mfma16(a[0][kk], bfrag, acc0);
      acc1 = mfma16(a[1][kk], bfrag, acc1);
    }
    int col = nt*16 + lr;
    if (proj == 2){
      #pragma unroll
      for (int r=0;r<4;r++){
        int row0 = r0 + lg*4 + r;
        int row1 = row0 + 16;
        vtb[(((size_t)(h*B_SZ + (row0>>11))*E_DIM + col) << 11) + (row0 & 2047)] = f2bf(acc0[r]);
        vtb[(((size_t)(h*B_SZ + (row1>>11))*E_DIM + col) << 11) + (row1 & 2047)] = f2bf(acc1[r]);
      }
    } else {
      #pragma unroll
      for (int r=0;r<4;r++){
        int row0 = r0 + lg*4 + r;
        outp[(size_t)row0*E_DIM + col] = f2bf(acc0[r]);
        outp[(size_t)(row0+16)*E_DIM + col] = f2bf(acc1[r]);
      }
    }
  }
}

// ---------------- Kernel 4: flash attention + gate + residual LN ----------------
// 32 Q-rows/wave, 128/block, grid 256 (XCD-grouped). K and V both via global_load_lds
// with pre-swizzled global source; dbuf; 1 barrier/iter; defer-max softmax.
__global__ __launch_bounds__(256,1) void k_attn(
    const unsigned short* __restrict__ qb, const unsigned short* __restrict__ kb,
    const unsigned short* __restrict__ vt, const unsigned short* __restrict__ gp,
    const float* __restrict__ mval, const float* __restrict__ x,
    const float* __restrict__ g_res, const float* __restrict__ b_res,
    unsigned short* __restrict__ attout){
  int id = blockIdx.x;
  int hb = (id & 7) + ((id >> 7) << 3);      // blocks of same (h,b) land on same XCD
  int h = hb >> 2, bbx = hb & 3;
  int nblk = (id >> 3) & 15;
  int tid = threadIdx.x;
  int wv = tid >> 6, lane = tid & 63;
  int lr = lane & 15, lg = lane >> 4;
  int n0 = nblk * 128 + wv * 32;
  const unsigned short* qm = qb + ((size_t)h * ROWS + (size_t)bbx * N_SEQ) * E_DIM;
  const unsigned short* km = kb + ((size_t)h * ROWS + (size_t)bbx * N_SEQ) * E_DIM;
  const unsigned short* vm = vt + ((size_t)(h * B_SZ + bbx)) * E_DIM * N_SEQ;
  const unsigned short* gpm = gp + ((size_t)h * ROWS + (size_t)bbx * N_SEQ) * E_DIM;
  const float* mrow = mval + bbx * N_SEQ;

  __shared__ alignas(16) unsigned short Klds[2][32*256];   // linear dest, contents row-swizzled ((row&7)<<4)
  __shared__ alignas(16) unsigned short Vlds[2][256*32];   // logical [256 e][32 k], 64B rows, swizzled ((e&3)<<4)
  __shared__ alignas(16) unsigned short Plds[4][32][40];   // per-wave P (32 q-rows)

  short8 qf0[8], qf1[8];
  {
    const unsigned short* qr0 = qm + (size_t)(n0 + lr) * E_DIM + lg * 8;
    const unsigned short* qr1 = qm + (size_t)(n0 + 16 + lr) * E_DIM + lg * 8;
    #pragma unroll
    for (int kk=0;kk<8;kk++){
      qf0[kk] = *reinterpret_cast<const short8*>(qr0 + kk*32);
      qf1[kk] = *reinterpret_cast<const short8*>(qr1 + kk*32);
    }
  }
  f32x4 o0[16], o1[16];
  #pragma unroll
  for (int i=0;i<16;i++){ o0[i] = f32x4{0.f,0.f,0.f,0.f}; o1[i] = f32x4{0.f,0.f,0.f,0.f}; }
  float mr0[4], lr0_[4], mr1[4], lr1_[4];
  #pragma unroll
  for (int r=0;r<4;r++){ mr0[r] = -1.0e30f; lr0_[r] = 0.f; mr1[r] = -1.0e30f; lr1_[r] = 0.f; }

  // staging helpers (inline): K tile kt -> Klds[buf]; V tile kt -> Vlds[buf]
  #define STAGE_K(buf, kt_) { \
    const char* kgb = (const char*)(km + (size_t)(kt_)*32*E_DIM); \
    _Pragma("unroll") \
    for (int i=0;i<4;i++){ \
      int c = tid + i*256; int krow = c >> 5; \
      unsigned off = ((unsigned)(c*16)) ^ ((unsigned)((krow&7)<<4)); \
      GLOAD_LDS16(kgb + off, (char*)(&Klds[buf][0]) + c*16); \
    } }
  #define STAGE_V(buf, kt_) { \
    const char* vgb = (const char*)vm; \
    _Pragma("unroll") \
    for (int i=0;i<4;i++){ \
      int c = tid + i*256; int e = c >> 2; \
      unsigned w = (unsigned)(((c&3)*16) ^ ((e&3)<<4)); \
      GLOAD_LDS16(vgb + (size_t)e*(N_SEQ*2) + (size_t)(kt_)*64 + w, \
                  (char*)(&Vlds[buf][0]) + c*16); \
    } }

  STAGE_K(0, 0)
  STAGE_V(0, 0)
  __syncthreads();

  int cur = 0;
  for (int kt=0; kt<N_SEQ/32; kt++){
    int nxt = cur ^ 1;
    if (kt < N_SEQ/32 - 1){
      STAGE_K(nxt, kt+1)
      STAGE_V(nxt, kt+1)
    }
    // ---- QK^T: 32 rows x 32 cols ----
    const char* kbase = (const char*)(&Klds[cur][0]);
    f32x4 s00 = f32x4{0.f,0.f,0.f,0.f}, s01 = f32x4{0.f,0.f,0.f,0.f};
    f32x4 s10 = f32x4{0.f,0.f,0.f,0.f}, s11 = f32x4{0.f,0.f,0.f,0.f};
    unsigned swz = (unsigned)((lr&7)<<4);
    #pragma unroll
    for (int kk=0;kk<8;kk++){
      short8 b0 = *reinterpret_cast<const short8*>(kbase + ((unsigned)(lr*512 + kk*64 + lg*16) ^ swz));
      short8 b1 = *reinterpret_cast<const short8*>(kbase + ((unsigned)((16+lr)*512 + kk*64 + lg*16) ^ swz));
      s00 = mfma16(qf0[kk], b0, s00);
      s01 = mfma16(qf0[kk], b1, s01);
      s10 = mfma16(qf1[kk], b0, s10);
      s11 = mfma16(qf1[kk], b1, s11);
    }
    float mk0 = (mrow[kt*32 + lr] - 1.0f) * 1e9f;
    float mk1 = (mrow[kt*32 + 16 + lr] - 1.0f) * 1e9f;
    // ---- softmax group 0 (rows n0..n0+15) ----
    float p00[4], p01[4], t0[4];
    #pragma unroll
    for (int r=0;r<4;r++){
      p00[r] = s00[r]*0.0625f + mk0;
      p01[r] = s01[r]*0.0625f + mk1;
      t0[r] = fmaxf(p00[r], p01[r]);
    }
    #pragma unroll
    for (int m=1;m<16;m<<=1){
      #pragma unroll
      for (int r=0;r<4;r++) t0[r] = fmaxf(t0[r], __shfl_xor(t0[r], m, 16));
    }
    bool need0 = (t0[0] > mr0[0]+8.0f) || (t0[1] > mr0[1]+8.0f) || (t0[2] > mr0[2]+8.0f) || (t0[3] > mr0[3]+8.0f);
    if (__any((int)need0)){
      #pragma unroll
      for (int r=0;r<4;r++){
        float mnew = fmaxf(mr0[r], t0[r]);
        float alpha = __expf(mr0[r] - mnew);
        mr0[r] = mnew; lr0_[r] *= alpha;
        #pragma unroll
        for (int i=0;i<16;i++) o0[i][r] *= alpha;
      }
    }
    float rs0[4];
    #pragma unroll
    for (int r=0;r<4;r++){
      p00[r] = __expf(p00[r] - mr0[r]);
      p01[r] = __expf(p01[r] - mr0[r]);
      rs0[r] = p00[r] + p01[r];
    }
    #pragma unroll
    for (int m=1;m<16;m<<=1){
      #pragma unroll
      for (int r=0;r<4;r++) rs0[r] += __shfl_xor(rs0[r], m, 16);
    }
    #pragma unroll
    for (int r=0;r<4;r++) lr0_[r] += rs0[r];
    // ---- softmax group 1 (rows n0+16..n0+31) ----
    float p10[4], p11[4], t1[4];
    #pragma unroll
    for (int r=0;r<4;r++){
      p10[r] = s10[r]*0.0625f + mk0;
      p11[r] = s11[r]*0.0625f + mk1;
      t1[r] = fmaxf(p10[r], p11[r]);
    }
    #pragma unroll
    for (int m=1;m<16;m<<=1){
      #pragma unroll
      for (int r=0;r<4;r++) t1[r] = fmaxf(t1[r], __shfl_xor(t1[r], m, 16));
    }
    bool need1 = (t1[0] > mr1[0]+8.0f) || (t1[1] > mr1[1]+8.0f) || (t1[2] > mr1[2]+8.0f) || (t1[3] > mr1[3]+8.0f);
    if (__any((int)need1)){
      #pragma unroll
      for (int r=0;r<4;r++){
        float mnew = fmaxf(mr1[r], t1[r]);
        float alpha = __expf(mr1[r] - mnew);
        mr1[r] = mnew; lr1_[r] *= alpha;
        #pragma unroll
        for (int i=0;i<16;i++) o1[i][r] *= alpha;
      }
    }
    float rs1[4];
    #pragma unroll
    for (int r=0;r<4;r++){
      p10[r] = __expf(p10[r] - mr1[r]);
      p11[r] = __expf(p11[r] - mr1[r]);
      rs1[r] = p10[r] + p11[r];
    }
    #pragma unroll
    for (int m=1;m<16;m<<=1){
      #pragma unroll
      for (int r=0;r<4;r++) rs1[r] += __shfl_xor(rs1[r], m, 16);
    }
    #pragma unroll
    for (int r=0;r<4;r++) lr1_[r] += rs1[r];
    // ---- P -> LDS (wave-private) -> A-frags ----
    #pragma unroll
    for (int r=0;r<4;r++){
      Plds[wv][lg*4+r][lr]       = f2bf(p00[r]);
      Plds[wv][lg*4+r][16+lr]    = f2bf(p01[r]);
      Plds[wv][16+lg*4+r][lr]    = f2bf(p10[r]);
      Plds[wv][16+lg*4+r][16+lr] = f2bf(p11[r]);
    }
    short8 pa0 = *reinterpret_cast<const short8*>(&Plds[wv][lr][lg*8]);
    short8 pa1 = *reinterpret_cast<const short8*>(&Plds[wv][16+lr][lg*8]);
    // ---- PV ----
    const char* vbase = (const char*)(&Vlds[cur][0]);
    unsigned vswz = (unsigned)((lr&3)<<4);
    #pragma unroll
    for (int et=0;et<16;et++){
      short8 bv = *reinterpret_cast<const short8*>(vbase + ((unsigned)((et*16+lr)*64 + lg*16) ^ vswz));
      o0[et] = mfma16(pa0, bv, o0[et]);
      o1[et] = mfma16(pa1, bv, o1[et]);
    }
    __syncthreads();
    cur = nxt;
  }
  // ---- epilogue: /l, sigmoid gate, +x, LN(g_res,b_res), write head-major bf16 ----
  #pragma unroll
  for (int grp=0; grp<2; grp++){
    f32x4* o = grp ? o1 : o0;
    float* lrn = grp ? lr1_ : lr0_;
    int nb = n0 + grp*16;
    float inv[4];
    #pragma unroll
    for (int r=0;r<4;r++) inv[r] = (lrn[r] > 0.f) ? (1.0f / lrn[r]) : 0.f;
    float s1_[4] = {0,0,0,0}, s2_[4] = {0,0,0,0};
    #pragma unroll
    for (int et=0;et<16;et++){
      int col = et*16 + lr;
      #pragma unroll
      for (int r=0;r<4;r++){
        int n = nb + lg*4 + r;
        float ov = o[et][r] * inv[r];
        float gpre = bf2f(gpm[(size_t)n*E_DIM + col]);
        float gate = 1.0f / (1.0f + __expf(-gpre));
        float val = ov * gate + x[((size_t)(bbx*N_SEQ + n))*D_DIM + col];
        o[et][r] = val;
        s1_[r] += val; s2_[r] += val*val;
      }
    }
    #pragma unroll
    for (int m=1;m<16;m<<=1){
      #pragma unroll
      for (int r=0;r<4;r++){ s1_[r] += __shfl_xor(s1_[r], m, 16); s2_[r] += __shfl_xor(s2_[r], m, 16); }
    }
    float mm_[4], rsv[4];
    #pragma unroll
    for (int r=0;r<4;r++){
      float mean = s1_[r] * (1.0f/E_DIM);
      float var  = s2_[r] * (1.0f/E_DIM) - mean*mean;
      mm_[r] = mean; rsv[r] = rsqrtf(var + LN_EPS);
    }
    #pragma unroll
    for (int et=0;et<16;et++){
      int col = et*16 + lr;
      float gr = g_res[col], br = b_res[col];
      #pragma unroll
      for (int r=0;r<4;r++){
        int n = nb + lg*4 + r;
        float y = (o[et][r] - mm_[r]) * rsv[r] * gr + br;
        attout[((size_t)(bbx*N_SEQ + n))*1024 + h*256 + col] = f2bf(y);
      }
    }
  }
  #undef STAGE_K
  #undef STAGE_V
}

// ---------------- Kernel 5: out proj + bias + residual + LN + mask ----------------
__global__ __launch_bounds__(128) void k_final(
    const unsigned short* __restrict__ attout, const unsigned short* __restrict__ owt,
    const float* __restrict__ out_b, const float* __restrict__ x,
    const float* __restrict__ g_out, const float* __restrict__ b_out,
    const float* __restrict__ mval, float* __restrict__ out){
  int wv = threadIdx.x >> 6, lane = threadIdx.x & 63;
  int lr = lane & 15, lg = lane >> 4;
  int r0 = blockIdx.x * 32 + wv*16;
  f32x4 acc[16];
  #pragma unroll
  for (int i=0;i<16;i++) acc[i] = f32x4{0.f,0.f,0.f,0.f};
  const unsigned short* arow = attout + (size_t)(r0 + lr)*1024 + lg*8;
  for (int kg=0; kg<4; kg++){
    short8 a[8];
    #pragma unroll
    for (int kk=0;kk<8;kk++) a[kk] = *reinterpret_cast<const short8*>(arow + kg*256 + kk*32);
    #pragma unroll
    for (int nt=0;nt<16;nt++){
      const unsigned short* brow = owt + (size_t)(nt*16 + lr)*1024 + kg*256 + lg*8;
      #pragma unroll
      for (int kk=0;kk<8;kk++){
        short8 bfrag = *reinterpret_cast<const short8*>(brow + kk*32);
        acc[nt] = mfma16(a[kk], bfrag, acc[nt]);
      }
    }
  }
  float s1_[4]={0,0,0,0}, s2_[4]={0,0,0,0};
  #pragma unroll
  for (int nt=0;nt<16;nt++){
    int col = nt*16 + lr;
    float ob = out_b[col];
    #pragma unroll
    for (int r=0;r<4;r++){
      int row = r0 + lg*4 + r;
      float val = acc[nt][r] + ob + x[(size_t)row*D_DIM + col];
      acc[nt][r] = val;
      s1_[r]+=val; s2_[r]+=val*val;
    }
  }
  #pragma unroll
  for (int m=1;m<16;m<<=1){
    #pragma unroll
    for (int r=0;r<4;r++){ s1_[r]+=__shfl_xor(s1_[r],m,16); s2_[r]+=__shfl_xor(s2_[r],m,16); }
  }
  float mm_[4], rs_[4];
  #pragma unroll
  for (int r=0;r<4;r++){
    float mean = s1_[r]*(1.0f/E_DIM);
    float var  = s2_[r]*(1.0f/E_DIM) - mean*mean;
    mm_[r]=mean; rs_[r]=rsqrtf(var + LN_EPS);
  }
  #pragma unroll
  for (int nt=0;nt<16;nt++){
    int col = nt*16 + lr;
    float gg = g_out[col], bb2 = b_out[col];
    #pragma unroll
    for (int r=0;r<4;r++){
      int row = r0 + lg*4 + r;
      float y = ((acc[nt][r]-mm_[r])*rs_[r]*gg + bb2) * mval[row];
      out[(size_t)row*E_DIM + col] = y;
    }
  }
}

extern "C" void kernel_launch(void* const* d_in, const int* in_sizes, int n_in,
                              void* d_out, int out_size, void* d_ws, size_t ws_size,
                              hipStream_t stream) {
  const float* x     = (const float*)d_in[0];
  const float* mask  = (const float*)d_in[1];
  const float* Wq    = (const float*)d_in[2];
  const float* Wk    = (const float*)d_in[3];
  const float* Wv    = (const float*)d_in[4];
  const float* Wg    = (const float*)d_in[5];
  const float* out_w = (const float*)d_in[6];
  const float* out_b = (const float*)d_in[7];
  const float* g_in  = (const float*)d_in[8];
  const float* b_in  = (const float*)d_in[9];
  const float* g_res = (const float*)d_in[10];
  const float* b_res = (const float*)d_in[11];
  const float* g_out = (const float*)d_in[12];
  const float* b_out = (const float*)d_in[13];

  char* ws = (char*)d_ws;
  size_t off = 0;
  unsigned short* xn   = (unsigned short*)(ws + off); off += (size_t)ROWS * D_DIM * 2;           // 4 MB
  float*          mval = (float*)(ws + off);          off += (size_t)ROWS * 4;                   // 32 KB
  unsigned short* wt   = (unsigned short*)(ws + off); off += (size_t)16 * D_DIM * E_DIM * 2;     // 2 MB
  unsigned short* owt  = (unsigned short*)(ws + off); off += (size_t)E_DIM * 1024 * 2;           // 512 KB
  unsigned short* qb   = (unsigned short*)(ws + off); off += (size_t)H_HEADS * ROWS * E_DIM * 2; // 16 MB
  unsigned short* kb   = (unsigned short*)(ws + off); off += (size_t)H_HEADS * ROWS * E_DIM * 2; // 16 MB
  unsigned short* vtb  = (unsigned short*)(ws + off); off += (size_t)H_HEADS * ROWS * E_DIM * 2; // 16 MB
  unsigned short* gpb  = (unsigned short*)(ws + off); off += (size_t)H_HEADS * ROWS * E_DIM * 2; // 16 MB
  unsigned short* attout = (unsigned short*)(ws + off); off += (size_t)ROWS * 1024 * 2;          // 16 MB

  k_ln_in<<<dim3(ROWS/4), dim3(256), 0, stream>>>(x, mask, g_in, b_in, xn, mval);
  k_prep_w<<<dim3(4,4,16), dim3(256), 0, stream>>>(Wq, Wk, Wv, Wg, wt);
  k_prep_ow<<<dim3(16,4), dim3(256), 0, stream>>>(out_w, owt);
  k_proj<<<dim3(ROWS/128, 16), dim3(256), 0, stream>>>(xn, wt, qb, kb, vtb, gpb);
  k_attn<<<dim3(256), dim3(256), 0, stream>>>(qb, kb, vtb, gpb, mval, x, g_res, b_res, attout);
  k_final<<<dim3(ROWS/32), dim3(128), 0, stream>>>(attout, owt, out_b, x, g_out, b_out, mval, (float*)d_out);
}